// Round 2
// baseline (326.703 us; speedup 1.0000x reference)
//
#include <hip/hip_runtime.h>
#include <hip/hip_cooperative_groups.h>

namespace cg = cooperative_groups;

// ---------------------------------------------------------------------------
// GenView, round 11.
//
// Algebra (verified R1-R8): per-row softmax cancels emb[row]·w1 and biases.
//   q[n]    = feat[n] . (W @ w2)
//   t[n]    = exp( sum_{e:row=n} v[e]*q[col[e]] )
//   invS[n] = 1 / sum_{e:row=n} t[col[e]]
//   out[e]  = vori[e] + t[col[e]] * invS[row[e]]
//
// R9 = 207.8 us (5 dispatches, ~63 us kernel work vs ~30 us analytic; rest
// is gaps+ramps). R10's manual spin-barrier mega-kernel killed the container
// (co-residency not enforceable for a plain launch -> bounded spin = seconds
// per launch under rocprof replay). R11 = same single-dispatch theory via the
// SANCTIONED mechanism: hipLaunchCooperativeKernel + this_grid().sync().
//  - Co-residency guaranteed by cooperative-launch semantics (launch errors
//    out if grid too big; grid sized from the occupancy API).
//  - No spin loops: launch failure -> clear error -> verified R9 path.
//  - P0 folds k_prep in (u2 = W@w2 via one wave per f; zero cnt).
// Bucket sort unchanged: row>>7 -> 391 buckets, CAP=3072 (mean 2046,
// 11+ sigma), LDS hist -> global reserve -> scatter.
// ---------------------------------------------------------------------------

typedef unsigned int u32;

#define RPB     128          // rows per bucket
#define CAP     3072         // record slots per bucket
#define NB_MAX  512          // max buckets (N <= 65536)
#define SB      256          // sort blocks (fallback k_fused)
#define GB      782          // gemv blocks (fallback k_fused)

// ---- u2[f] = sum_h W[f,h]*mw[H+h]; block 0 also zeros cnt[] (fallback) ----
__global__ void k_prep(const float* __restrict__ W, const float* __restrict__ mw,
                       float* __restrict__ u2, u32* __restrict__ cnt,
                       int F, int H, int nz) {
  if (blockIdx.x == 0)
    for (int s = threadIdx.x; s < nz; s += blockDim.x) cnt[s] = 0;
  int f = blockIdx.x * blockDim.x + threadIdx.x;
  if (f >= F) return;
  const float4* wr = (const float4*)(W + (size_t)f * H);
  const float4* mv = (const float4*)(mw + H);
  float s = 0.f;
  for (int i = 0; i < H / 4; ++i) {
    float4 a = wr[i], b = mv[i];
    s = fmaf(a.x, b.x, fmaf(a.y, b.y, fmaf(a.z, b.z, fmaf(a.w, b.w, s))));
  }
  u2[f] = s;
}

// ---- cooperative mega-kernel: prep | sort+gemv | t | invS | out ----
// Requires F==512, H==128. Grid sized by occupancy API so the cooperative
// launch is legal; cg::this_grid().sync() between phases.
template <int F, int H>
__global__ void __launch_bounds__(1024)
k_mega(const int* __restrict__ row, const int* __restrict__ col,
       const float* __restrict__ vori, const float* __restrict__ feat,
       const float* __restrict__ W, const float* __restrict__ mw,
       float* __restrict__ u2, float* __restrict__ q,
       float* __restrict__ t, float* __restrict__ invS,
       u32* __restrict__ cnt, uint2* __restrict__ rec8,
       float* __restrict__ out, int E, int N, int nb) {
  __shared__ u32 h[NB_MAX];
  __shared__ u32 start[NB_MAX];
  __shared__ float acc[RPB];
  const int tid  = threadIdx.x;
  const int lane = tid & 63;
  const int G    = gridDim.x;
  cg::grid_group grid = cg::this_grid();

  // ---------------- P0: u2[f] = W[f,:].mw[H:], one wave per f; zero cnt ----
  {
    const int w = blockIdx.x * (1024 >> 6) + (tid >> 6);
    if (w < F) {
      // H == 128: each lane covers 2 consecutive floats
      float2 a = *(const float2*)(W + (size_t)w * H + lane * 2);
      float2 b = *(const float2*)(mw + H + lane * 2);
      float s = fmaf(a.x, b.x, a.y * b.y);
      s += __shfl_xor(s, 32);
      s += __shfl_xor(s, 16);
      s += __shfl_xor(s, 8);
      s += __shfl_xor(s, 4);
      s += __shfl_xor(s, 2);
      s += __shfl_xor(s, 1);
      if (lane == 0) u2[w] = s;
    }
    if (blockIdx.x == G - 1)
      for (int s2 = tid; s2 < nb; s2 += 1024) cnt[s2] = 0;
  }

  grid.sync();

  // ---------------- P1a: bucket-sort my chunk of edges ----------------
  {
    const int chunk = (E + G - 1) / G;
    for (int s = tid; s < nb; s += 1024) h[s] = 0;
    __syncthreads();
    const int lo = blockIdx.x * chunk;
    const int hi = min(E, lo + chunk);
    for (int e = lo + tid; e < hi; e += 1024)
      atomicAdd(&h[row[e] >> 7], 1u);
    __syncthreads();
    for (int s = tid; s < nb; s += 1024) {
      u32 c = h[s];
      start[s] = c ? atomicAdd(&cnt[s], c) : 0u;  // device-scope reservation
      h[s] = 0u;                                  // reuse as local rank
    }
    __syncthreads();
    for (int e = lo + tid; e < hi; e += 1024) {
      int r = row[e];
      int b = r >> 7;
      u32 rank = atomicAdd(&h[b], 1u);
      u32 off  = min(start[b] + rank, (u32)(CAP - 1));  // memory-safety clamp
      rec8[(size_t)b * CAP + off] =
          make_uint2(((u32)col[e] << 7) | (u32)(r & 127),
                     __float_as_uint(vori[e]));
    }
  }

  // ---------------- P1b: gemv, ALL waves, static stride ----------------
  {
    const float4 ua = *(const float4*)(u2 + lane * 8);
    const float4 ub = *(const float4*)(u2 + lane * 8 + 4);
    const int wid = blockIdx.x * (1024 >> 6) + (tid >> 6);
    const int nw  = G * (1024 >> 6);
    for (int r = wid; r < N; r += nw) {
      const float* fr = feat + (size_t)r * F + lane * 8;
      float4 a = *(const float4*)fr;
      float4 b = *(const float4*)(fr + 4);
      float s = fmaf(a.x, ua.x, fmaf(a.y, ua.y, fmaf(a.z, ua.z,
                fmaf(a.w, ua.w, fmaf(b.x, ub.x, fmaf(b.y, ub.y,
                fmaf(b.z, ub.z, b.w * ub.w)))))));
      s += __shfl_xor(s, 32);
      s += __shfl_xor(s, 16);
      s += __shfl_xor(s, 8);
      s += __shfl_xor(s, 4);
      s += __shfl_xor(s, 2);
      s += __shfl_xor(s, 1);
      if (lane == 0) q[r] = s;
    }
  }

  grid.sync();

  // ---------------- P2: t[row] = exp( sum v * q[col] ) ----------------
  for (int b = blockIdx.x; b < nb; b += G) {
    if (tid < RPB) acc[tid] = 0.f;
    __syncthreads();
    const u32 lo = (u32)b * CAP;
    const u32 n  = min(cnt[b], (u32)CAP);
    for (u32 i = tid; i < n; i += 1024) {
      uint2 rr = rec8[lo + i];
      atomicAdd(&acc[rr.x & 127], q[rr.x >> 7] * __uint_as_float(rr.y));
    }
    __syncthreads();
    if (tid < RPB) t[b * RPB + tid] = __expf(acc[tid]);
    __syncthreads();
  }

  grid.sync();

  // ---------------- P3: invS[row] = 1 / sum t[col] ----------------
  for (int b = blockIdx.x; b < nb; b += G) {
    if (tid < RPB) acc[tid] = 0.f;
    __syncthreads();
    const u32 lo = (u32)b * CAP;
    const u32 n  = min(cnt[b], (u32)CAP);
    for (u32 i = tid; i < n; i += 1024) {
      uint2 rr = rec8[lo + i];
      atomicAdd(&acc[rr.x & 127], t[rr.x >> 7]);
    }
    __syncthreads();
    if (tid < RPB) invS[b * RPB + tid] = 1.0f / acc[tid]; // empty rows never read
    __syncthreads();
  }

  grid.sync();

  // ---------------- P4: out[e] = vori[e] + t[col]*invS[row] ----------------
  {
    const int e4n  = (E + 3) >> 2;
    const int gtid = blockIdx.x * 1024 + tid;
    const int step = G * 1024;
    for (int i = gtid; i < e4n; i += step) {
      int e = i * 4;
      if (e + 3 < E) {
        int4   r4 = *(const int4*)(row + e);
        int4   c4 = *(const int4*)(col + e);
        float4 v4 = *(const float4*)(vori + e);
        float4 o;
        o.x = v4.x + t[c4.x] * invS[r4.x];
        o.y = v4.y + t[c4.y] * invS[r4.y];
        o.z = v4.z + t[c4.z] * invS[r4.z];
        o.w = v4.w + t[c4.w] * invS[r4.w];
        *(float4*)(out + e) = o;
      } else {
        for (; e < E; ++e)
          out[e] = vori[e] + t[col[e]] * invS[row[e]];
      }
    }
  }
}

// ===================== fallback path (R9, verified 207.8 us) =====================

__global__ void __launch_bounds__(1024)
k_fused(const int* __restrict__ row, const int* __restrict__ col,
        const float* __restrict__ v, const float* __restrict__ feat,
        const float* __restrict__ u2, float* __restrict__ q,
        u32* __restrict__ cnt, uint2* __restrict__ rec8,
        int E, int N, int nb, int F) {
  __shared__ u32 h[NB_MAX];
  __shared__ u32 start[NB_MAX];
  const int tid = threadIdx.x;

  if (blockIdx.x < SB) {
    const int chunk = (E + SB - 1) / SB;
    for (int s = tid; s < nb; s += blockDim.x) h[s] = 0;
    __syncthreads();
    const int lo = blockIdx.x * chunk;
    const int hi = min(E, lo + chunk);
    for (int e = lo + tid; e < hi; e += blockDim.x)
      atomicAdd(&h[row[e] >> 7], 1u);
    __syncthreads();
    for (int s = tid; s < nb; s += blockDim.x) {
      u32 c = h[s];
      start[s] = c ? atomicAdd(&cnt[s], c) : 0u;
      h[s] = 0u;
    }
    __syncthreads();
    for (int e = lo + tid; e < hi; e += blockDim.x) {
      int r = row[e];
      int b = r >> 7;
      u32 rank = atomicAdd(&h[b], 1u);
      u32 off  = min(start[b] + rank, (u32)(CAP - 1));
      rec8[(size_t)b * CAP + off] =
          make_uint2(((u32)col[e] << 7) | (u32)(r & 127),
                     __float_as_uint(v[e]));
    }
  } else {
    const int lane = tid & 63;
    const float4 ua = *(const float4*)(u2 + lane * 8);
    const float4 ub = *(const float4*)(u2 + lane * 8 + 4);
    const int wid = (blockIdx.x - SB) * (1024 >> 6) + (tid >> 6);
    const int nw  = GB * (1024 >> 6);
    for (int r = wid; r < N; r += nw) {
      const float* fr = feat + (size_t)r * 512 + lane * 8;
      float4 a = *(const float4*)fr;
      float4 b = *(const float4*)(fr + 4);
      float s = fmaf(a.x, ua.x, fmaf(a.y, ua.y, fmaf(a.z, ua.z,
                fmaf(a.w, ua.w, fmaf(b.x, ub.x, fmaf(b.y, ub.y,
                fmaf(b.z, ub.z, b.w * ub.w)))))));
      s += __shfl_xor(s, 32);
      s += __shfl_xor(s, 16);
      s += __shfl_xor(s, 8);
      s += __shfl_xor(s, 4);
      s += __shfl_xor(s, 2);
      s += __shfl_xor(s, 1);
      if (lane == 0) q[r] = s;
    }
  }
}

__global__ void __launch_bounds__(1024)
k_sum_t(const uint2* __restrict__ rec8, const u32* __restrict__ cnt,
        const float* __restrict__ q, float* __restrict__ t) {
  __shared__ float acc[RPB];
  const int b = blockIdx.x;
  const int tid = threadIdx.x;
  if (tid < RPB) acc[tid] = 0.f;
  __syncthreads();
  const u32 lo = (u32)b * CAP;
  const u32 n  = min(cnt[b], (u32)CAP);
  for (u32 i = tid; i < n; i += blockDim.x) {
    uint2 rr = rec8[lo + i];
    atomicAdd(&acc[rr.x & 127], q[rr.x >> 7] * __uint_as_float(rr.y));
  }
  __syncthreads();
  if (tid < RPB) t[b * RPB + tid] = __expf(acc[tid]);
}

__global__ void __launch_bounds__(1024)
k_sum_invS(const uint2* __restrict__ rec8, const u32* __restrict__ cnt,
           const float* __restrict__ t, float* __restrict__ invS) {
  __shared__ float acc[RPB];
  const int b = blockIdx.x;
  const int tid = threadIdx.x;
  if (tid < RPB) acc[tid] = 0.f;
  __syncthreads();
  const u32 lo = (u32)b * CAP;
  const u32 n  = min(cnt[b], (u32)CAP);
  for (u32 i = tid; i < n; i += blockDim.x) {
    uint2 rr = rec8[lo + i];
    atomicAdd(&acc[rr.x & 127], t[rr.x >> 7]);
  }
  __syncthreads();
  if (tid < RPB) invS[b * RPB + tid] = 1.0f / acc[tid];
}

__global__ void k_out(const int* __restrict__ row, const int* __restrict__ col,
                      const float* __restrict__ vori, const float* __restrict__ t,
                      const float* __restrict__ invS, float* __restrict__ out,
                      int E) {
  int e4 = blockIdx.x * blockDim.x + threadIdx.x;
  int e  = e4 * 4;
  if (e + 3 < E) {
    int4   r4 = *(const int4*)(row + e);
    int4   c4 = *(const int4*)(col + e);
    float4 v4 = *(const float4*)(vori + e);
    float4 o;
    o.x = v4.x + t[c4.x] * invS[r4.x];
    o.y = v4.y + t[c4.y] * invS[r4.y];
    o.z = v4.z + t[c4.z] * invS[r4.z];
    o.w = v4.w + t[c4.w] * invS[r4.w];
    *(float4*)(out + e) = o;
  } else {
    for (; e < E; ++e)
      out[e] = vori[e] + t[col[e]] * invS[row[e]];
  }
}

// ---- last-resort fallback (ws too small / shape mismatch): global-atomic ----
__global__ void k_gemv_fb(const float* __restrict__ feat, const float* __restrict__ u2,
                          float* __restrict__ q, int N, int F) {
  const int lane = threadIdx.x & 63;
  const int wave = (blockIdx.x * blockDim.x + threadIdx.x) >> 6;
  if (wave >= N) return;
  const float* fr = feat + (size_t)wave * F;
  float a = 0.f;
  for (int i = lane; i < F; i += 64) a = fmaf(fr[i], u2[i], a);
  for (int off = 32; off; off >>= 1) a += __shfl_xor(a, off);
  if (lane == 0) q[wave] = a;
}
__global__ void k_scatter_B_at(const int* __restrict__ row, const int* __restrict__ col,
                               const float* __restrict__ v, const float* __restrict__ q,
                               float* __restrict__ B, int E) {
  int e = blockIdx.x * blockDim.x + threadIdx.x;
  if (e >= E) return;
  atomicAdd(&B[row[e]], v[e] * q[col[e]]);
}
__global__ void k_node_t(const float* __restrict__ B, float* __restrict__ t, int N) {
  int n = blockIdx.x * blockDim.x + threadIdx.x;
  if (n < N) t[n] = __expf(B[n]);
}
__global__ void k_scatter_S_at(const int* __restrict__ row, const int* __restrict__ col,
                               const float* __restrict__ t, float* __restrict__ S, int E) {
  int e = blockIdx.x * blockDim.x + threadIdx.x;
  if (e >= E) return;
  atomicAdd(&S[row[e]], t[col[e]]);
}
__global__ void k_out_div(const int* __restrict__ row, const int* __restrict__ col,
                          const float* __restrict__ vori, const float* __restrict__ t,
                          const float* __restrict__ S, float* __restrict__ out, int E) {
  int e = blockIdx.x * blockDim.x + threadIdx.x;
  if (e >= E) return;
  out[e] = vori[e] + t[col[e]] / S[row[e]];
}

extern "C" void kernel_launch(void* const* d_in, const int* in_sizes, int n_in,
                              void* d_out, int out_size, void* d_ws, size_t ws_size,
                              hipStream_t stream) {
  const float* vori = (const float*)d_in[0];
  const float* feat = (const float*)d_in[1];
  const int*   vind = (const int*)d_in[2];
  const float* W    = (const float*)d_in[4];
  const float* mw   = (const float*)d_in[6];

  const int E = in_sizes[0];
  const int H = in_sizes[6] / 2;        // 128
  const int F = in_sizes[4] / H;        // 512
  const int N = in_sizes[1] / F;        // 50000

  const int* row = vind;
  const int* col = vind + E;

  const int nb   = (N + RPB - 1) / RPB; // 391
  const int npad = nb * RPB;

  // ---- workspace: u2(F) q(N) t(npad) invS(npad) | cnt(nb) pad(8) | rec8 ----
  float* ws   = (float*)d_ws;
  float* u2   = ws;
  float* q    = u2 + F;
  float* t    = q + N;
  float* invS = t + npad;
  u32*   cnt  = (u32*)(invS + npad);
  size_t hdr  = (size_t)((char*)(cnt + nb + 8) - (char*)d_ws);
  hdr = (hdr + 15) & ~(size_t)15;
  uint2* rec8 = (uint2*)((char*)d_ws + hdr);
  size_t need = hdr + (size_t)nb * CAP * sizeof(uint2);

  // one-time host queries: cooperative support + co-resident grid size
  static int G_cached = -2;             // -2 = not yet queried; 0 = unusable
  if (G_cached == -2) {
    int dev = 0, coop = 0, cus = 0, bpc = 0;
    hipGetDevice(&dev);
    hipError_t ea = hipDeviceGetAttribute(&coop, hipDeviceAttributeCooperativeLaunch, dev);
    hipError_t eb = hipDeviceGetAttribute(&cus, hipDeviceAttributeMultiprocessorCount, dev);
    hipError_t ec = hipOccupancyMaxActiveBlocksPerMultiprocessor(&bpc, k_mega<512, 128>, 1024, 0);
    if (ea == hipSuccess && eb == hipSuccess && ec == hipSuccess &&
        coop != 0 && bpc > 0 && cus > 0) {
      if (bpc > 2) bpc = 2;            // 16 waves/block, 32 waves/CU cap
      G_cached = bpc * cus;
    } else {
      G_cached = 0;
    }
  }
  const int G = G_cached;

  bool done = false;
  if (G >= 64 && ws_size >= need && F == 512 && H == 128 && nb <= NB_MAX) {
    // ---- R11: single cooperative dispatch, 4 grid syncs ----
    float* outp = (float*)d_out;
    void* kargs[] = {
      (void*)&row, (void*)&col, (void*)&vori, (void*)&feat,
      (void*)&W,   (void*)&mw,  (void*)&u2,   (void*)&q,
      (void*)&t,   (void*)&invS,(void*)&cnt,  (void*)&rec8,
      (void*)&outp,(void*)&E,   (void*)&N,    (void*)&nb
    };
    hipError_t el = hipLaunchCooperativeKernel(
        reinterpret_cast<const void*>(&k_mega<512, 128>),
        dim3(G), dim3(1024), kargs, 0, stream);
    if (el == hipSuccess) {
      done = true;
    } else {
      (void)hipGetLastError();          // clear, fall back
      G_cached = 0;
    }
  }

  if (!done) {
    k_prep<<<(F + 255) / 256, 256, 0, stream>>>(W, mw, u2, cnt, F, H, nb + 8);
    if (ws_size >= need && F == 512 && H % 4 == 0 && nb <= NB_MAX) {
      // ---- R9 path (verified) ----
      k_fused<<<SB + GB, 1024, 0, stream>>>(row, col, vori, feat, u2, q,
                                            cnt, rec8, E, N, nb, F);
      k_sum_t<<<nb, 1024, 0, stream>>>(rec8, cnt, q, t);
      k_sum_invS<<<nb, 1024, 0, stream>>>(rec8, cnt, t, invS);
      const int e4 = (E + 3) / 4;
      k_out<<<(e4 + 255) / 256, 256, 0, stream>>>(row, col, vori, t, invS,
                                                  (float*)d_out, E);
    } else {
      const int eb  = (E + 255) / 256;
      const int nbk = (N + 255) / 256;
      float* S = invS;
      k_gemv_fb<<<(N * 64 + 255) / 256, 256, 0, stream>>>(feat, u2, q, N, F);
      hipMemsetAsync((void*)S, 0, sizeof(float) * (size_t)npad, stream);
      k_scatter_B_at<<<eb, 256, 0, stream>>>(row, col, vori, q, S, E);
      k_node_t<<<nbk, 256, 0, stream>>>(S, t, N);
      hipMemsetAsync((void*)S, 0, sizeof(float) * (size_t)npad, stream);
      k_scatter_S_at<<<eb, 256, 0, stream>>>(row, col, t, S, E);
      k_out_div<<<eb, 256, 0, stream>>>(row, col, vori, t, S, (float*)d_out, E);
    }
  }
}

// Round 3
// 216.502 us; speedup vs baseline: 1.5090x; 1.5090x over previous
//
#include <hip/hip_runtime.h>

// ---------------------------------------------------------------------------
// GenView, round 12.
//
// Algebra (verified R1-R8): per-row softmax cancels emb[row]·w1 and biases.
//   q[n]    = feat[n] . (W @ w2)
//   t[n]    = exp( sum_{e:row=n} v[e]*q[col[e]] )
//   invS[n] = 1 / sum_{e:row=n} t[col[e]]
//   out[e]  = vori[e] + t[col[e]] * invS[row[e]]
//
// History: R9 = 207.8 us (5 dispatches). R10 manual-spin mega-kernel killed
// the container. R11 cooperative mega-kernel PASSED but k_mega = 266 us,
// VALUBusy 1.4%, HBM 4% -> grid.sync() spins ~60 us each on this chip
// (device-scope spin across 8 non-coherent XCD L2s). Grid-wide sync is
// strictly worse than dispatch gaps here. R12 = plain dispatches again:
//  - k_fused1r: 512 blocks (exactly 2/CU, ONE occupancy round), every block
//    sorts its edge chunk then joins the grid-stride gemv. Removes R9's
//    half-empty second round. Sort also records edge id (recE).
//  - k_sum_t: unchanged from verified R9.
//  - k_finish: fuses invS + out. Per bucket: t[col] gathered once into
//    registers (<=3 records/thread), LDS-sum -> invS in LDS -> scatter
//    out[e] = v + t[col]*invS[row] straight from registers. Kills k_out's
//    9.6 MB re-read and one dispatch gap. 5 dispatches -> 4.
// Bucket sort unchanged: row>>7 -> 391 buckets, CAP=3072 (mean 2046,
// 11+ sigma), LDS hist -> global reserve -> scatter.
// ---------------------------------------------------------------------------

typedef unsigned int u32;

#define RPB     128          // rows per bucket
#define CAP     3072         // record slots per bucket (== 3*1024)
#define NB_MAX  512          // max buckets (N <= 65536)
#define FG      512          // fused grid: 2 blocks/CU x 256 CU, one round
#define SB      256          // sort blocks (fallback k_fused)
#define GB      782          // gemv blocks (fallback k_fused)

// ---- u2[f] = sum_h W[f,h]*mw[H+h]; block 0 also zeros cnt[] ----
__global__ void k_prep(const float* __restrict__ W, const float* __restrict__ mw,
                       float* __restrict__ u2, u32* __restrict__ cnt,
                       int F, int H, int nz) {
  if (blockIdx.x == 0)
    for (int s = threadIdx.x; s < nz; s += blockDim.x) cnt[s] = 0;
  int f = blockIdx.x * blockDim.x + threadIdx.x;
  if (f >= F) return;
  const float4* wr = (const float4*)(W + (size_t)f * H);
  const float4* mv = (const float4*)(mw + H);
  float s = 0.f;
  for (int i = 0; i < H / 4; ++i) {
    float4 a = wr[i], b = mv[i];
    s = fmaf(a.x, b.x, fmaf(a.y, b.y, fmaf(a.z, b.z, fmaf(a.w, b.w, s))));
  }
  u2[f] = s;
}

// ---- single-round fused: every block sorts its chunk, then gemv ----
template <int F>
__global__ void __launch_bounds__(1024)
k_fused1r(const int* __restrict__ row, const int* __restrict__ col,
          const float* __restrict__ v, const float* __restrict__ feat,
          const float* __restrict__ u2, float* __restrict__ q,
          u32* __restrict__ cnt, uint2* __restrict__ rec8,
          u32* __restrict__ recE, int E, int N, int nb) {
  __shared__ u32 h[NB_MAX];
  __shared__ u32 start[NB_MAX];
  const int tid = threadIdx.x;
  const int G   = gridDim.x;

  // ---------------- sort my chunk of edges ----------------
  {
    const int chunk = (E + G - 1) / G;
    for (int s = tid; s < nb; s += 1024) h[s] = 0;
    __syncthreads();
    const int lo = blockIdx.x * chunk;
    const int hi = min(E, lo + chunk);
    for (int e = lo + tid; e < hi; e += 1024)
      atomicAdd(&h[row[e] >> 7], 1u);
    __syncthreads();
    for (int s = tid; s < nb; s += 1024) {
      u32 c = h[s];
      start[s] = c ? atomicAdd(&cnt[s], c) : 0u;  // device-scope reservation
      h[s] = 0u;                                  // reuse as local rank
    }
    __syncthreads();
    for (int e = lo + tid; e < hi; e += 1024) {
      int r = row[e];
      int b = r >> 7;
      u32 rank = atomicAdd(&h[b], 1u);
      u32 off  = min(start[b] + rank, (u32)(CAP - 1));  // memory-safety clamp
      size_t idx = (size_t)b * CAP + off;
      rec8[idx] = make_uint2(((u32)col[e] << 7) | (u32)(r & 127),
                             __float_as_uint(v[e]));
      recE[idx] = (u32)e;
    }
  }

  // ---------------- gemv, all waves, static stride ----------------
  {
    const int lane = tid & 63;
    const float4 ua = *(const float4*)(u2 + lane * 8);
    const float4 ub = *(const float4*)(u2 + lane * 8 + 4);
    const int wid = blockIdx.x * (1024 >> 6) + (tid >> 6);
    const int nw  = G * (1024 >> 6);
    for (int r = wid; r < N; r += nw) {
      const float* fr = feat + (size_t)r * F + lane * 8;
      float4 a = *(const float4*)fr;
      float4 b = *(const float4*)(fr + 4);
      float s = fmaf(a.x, ua.x, fmaf(a.y, ua.y, fmaf(a.z, ua.z,
                fmaf(a.w, ua.w, fmaf(b.x, ub.x, fmaf(b.y, ub.y,
                fmaf(b.z, ub.z, b.w * ub.w)))))));
      s += __shfl_xor(s, 32);
      s += __shfl_xor(s, 16);
      s += __shfl_xor(s, 8);
      s += __shfl_xor(s, 4);
      s += __shfl_xor(s, 2);
      s += __shfl_xor(s, 1);
      if (lane == 0) q[r] = s;
    }
  }
}

// ---- per-bucket: t[row] = exp( sum v * q[col] )  (verified R9 kernel) ----
__global__ void __launch_bounds__(1024)
k_sum_t(const uint2* __restrict__ rec8, const u32* __restrict__ cnt,
        const float* __restrict__ q, float* __restrict__ t) {
  __shared__ float acc[RPB];
  const int b = blockIdx.x;
  const int tid = threadIdx.x;
  if (tid < RPB) acc[tid] = 0.f;
  __syncthreads();
  const u32 lo = (u32)b * CAP;
  const u32 n  = min(cnt[b], (u32)CAP);
  for (u32 i = tid; i < n; i += blockDim.x) {
    uint2 rr = rec8[lo + i];
    atomicAdd(&acc[rr.x & 127], q[rr.x >> 7] * __uint_as_float(rr.y));
  }
  __syncthreads();
  if (tid < RPB) t[b * RPB + tid] = __expf(acc[tid]);
}

// ---- per-bucket fused: invS in LDS, then out[e] = v + t[col]*invS[row] ----
// CAP == 3*1024 so <=3 records/thread, all held in registers (static idx).
__global__ void __launch_bounds__(1024)
k_finish(const uint2* __restrict__ rec8, const u32* __restrict__ recE,
         const u32* __restrict__ cnt, const float* __restrict__ t,
         float* __restrict__ out) {
  __shared__ float acc[RPB];
  const int b = blockIdx.x;
  const int tid = threadIdx.x;
  if (tid < RPB) acc[tid] = 0.f;
  __syncthreads();
  const u32 lo = (u32)b * CAP;
  const u32 n  = min(cnt[b], (u32)CAP);
  bool  ok[3];
  u32   cr[3], ee[3];
  float vv[3], tc[3];
#pragma unroll
  for (int k = 0; k < 3; ++k) {
    u32 i = (u32)tid + (u32)k * 1024u;
    ok[k] = (i < n);
    cr[k] = 0; ee[k] = 0; vv[k] = 0.f; tc[k] = 0.f;
    if (ok[k]) {
      uint2 rr = rec8[lo + i];
      cr[k] = rr.x;
      vv[k] = __uint_as_float(rr.y);
      ee[k] = recE[lo + i];
      float tv = t[rr.x >> 7];
      tc[k] = tv;
      atomicAdd(&acc[rr.x & 127], tv);
    }
  }
  __syncthreads();
  if (tid < RPB) acc[tid] = 1.0f / acc[tid];   // empty rows never read
  __syncthreads();
#pragma unroll
  for (int k = 0; k < 3; ++k)
    if (ok[k])
      out[ee[k]] = vv[k] + tc[k] * acc[cr[k] & 127];
}

// ===================== fallback path (R9, verified 207.8 us) =====================

__global__ void __launch_bounds__(1024)
k_fused(const int* __restrict__ row, const int* __restrict__ col,
        const float* __restrict__ v, const float* __restrict__ feat,
        const float* __restrict__ u2, float* __restrict__ q,
        u32* __restrict__ cnt, uint2* __restrict__ rec8,
        int E, int N, int nb, int F) {
  __shared__ u32 h[NB_MAX];
  __shared__ u32 start[NB_MAX];
  const int tid = threadIdx.x;

  if (blockIdx.x < SB) {
    const int chunk = (E + SB - 1) / SB;
    for (int s = tid; s < nb; s += blockDim.x) h[s] = 0;
    __syncthreads();
    const int lo = blockIdx.x * chunk;
    const int hi = min(E, lo + chunk);
    for (int e = lo + tid; e < hi; e += blockDim.x)
      atomicAdd(&h[row[e] >> 7], 1u);
    __syncthreads();
    for (int s = tid; s < nb; s += blockDim.x) {
      u32 c = h[s];
      start[s] = c ? atomicAdd(&cnt[s], c) : 0u;
      h[s] = 0u;
    }
    __syncthreads();
    for (int e = lo + tid; e < hi; e += blockDim.x) {
      int r = row[e];
      int b = r >> 7;
      u32 rank = atomicAdd(&h[b], 1u);
      u32 off  = min(start[b] + rank, (u32)(CAP - 1));
      rec8[(size_t)b * CAP + off] =
          make_uint2(((u32)col[e] << 7) | (u32)(r & 127),
                     __float_as_uint(v[e]));
    }
  } else {
    const int lane = tid & 63;
    const float4 ua = *(const float4*)(u2 + lane * 8);
    const float4 ub = *(const float4*)(u2 + lane * 8 + 4);
    const int wid = (blockIdx.x - SB) * (1024 >> 6) + (tid >> 6);
    const int nw  = GB * (1024 >> 6);
    for (int r = wid; r < N; r += nw) {
      const float* fr = feat + (size_t)r * 512 + lane * 8;
      float4 a = *(const float4*)fr;
      float4 b = *(const float4*)(fr + 4);
      float s = fmaf(a.x, ua.x, fmaf(a.y, ua.y, fmaf(a.z, ua.z,
                fmaf(a.w, ua.w, fmaf(b.x, ub.x, fmaf(b.y, ub.y,
                fmaf(b.z, ub.z, b.w * ub.w)))))));
      s += __shfl_xor(s, 32);
      s += __shfl_xor(s, 16);
      s += __shfl_xor(s, 8);
      s += __shfl_xor(s, 4);
      s += __shfl_xor(s, 2);
      s += __shfl_xor(s, 1);
      if (lane == 0) q[r] = s;
    }
  }
}

__global__ void __launch_bounds__(1024)
k_sum_invS(const uint2* __restrict__ rec8, const u32* __restrict__ cnt,
           const float* __restrict__ t, float* __restrict__ invS) {
  __shared__ float acc[RPB];
  const int b = blockIdx.x;
  const int tid = threadIdx.x;
  if (tid < RPB) acc[tid] = 0.f;
  __syncthreads();
  const u32 lo = (u32)b * CAP;
  const u32 n  = min(cnt[b], (u32)CAP);
  for (u32 i = tid; i < n; i += blockDim.x) {
    uint2 rr = rec8[lo + i];
    atomicAdd(&acc[rr.x & 127], t[rr.x >> 7]);
  }
  __syncthreads();
  if (tid < RPB) invS[b * RPB + tid] = 1.0f / acc[tid];
}

__global__ void k_out(const int* __restrict__ row, const int* __restrict__ col,
                      const float* __restrict__ vori, const float* __restrict__ t,
                      const float* __restrict__ invS, float* __restrict__ out,
                      int E) {
  int e4 = blockIdx.x * blockDim.x + threadIdx.x;
  int e  = e4 * 4;
  if (e + 3 < E) {
    int4   r4 = *(const int4*)(row + e);
    int4   c4 = *(const int4*)(col + e);
    float4 v4 = *(const float4*)(vori + e);
    float4 o;
    o.x = v4.x + t[c4.x] * invS[r4.x];
    o.y = v4.y + t[c4.y] * invS[r4.y];
    o.z = v4.z + t[c4.z] * invS[r4.z];
    o.w = v4.w + t[c4.w] * invS[r4.w];
    *(float4*)(out + e) = o;
  } else {
    for (; e < E; ++e)
      out[e] = vori[e] + t[col[e]] * invS[row[e]];
  }
}

// ---- last-resort fallback (ws too small / shape mismatch): global-atomic ----
__global__ void k_gemv_fb(const float* __restrict__ feat, const float* __restrict__ u2,
                          float* __restrict__ q, int N, int F) {
  const int lane = threadIdx.x & 63;
  const int wave = (blockIdx.x * blockDim.x + threadIdx.x) >> 6;
  if (wave >= N) return;
  const float* fr = feat + (size_t)wave * F;
  float a = 0.f;
  for (int i = lane; i < F; i += 64) a = fmaf(fr[i], u2[i], a);
  for (int off = 32; off; off >>= 1) a += __shfl_xor(a, off);
  if (lane == 0) q[wave] = a;
}
__global__ void k_scatter_B_at(const int* __restrict__ row, const int* __restrict__ col,
                               const float* __restrict__ v, const float* __restrict__ q,
                               float* __restrict__ B, int E) {
  int e = blockIdx.x * blockDim.x + threadIdx.x;
  if (e >= E) return;
  atomicAdd(&B[row[e]], v[e] * q[col[e]]);
}
__global__ void k_node_t(const float* __restrict__ B, float* __restrict__ t, int N) {
  int n = blockIdx.x * blockDim.x + threadIdx.x;
  if (n < N) t[n] = __expf(B[n]);
}
__global__ void k_scatter_S_at(const int* __restrict__ row, const int* __restrict__ col,
                               const float* __restrict__ t, float* __restrict__ S, int E) {
  int e = blockIdx.x * blockDim.x + threadIdx.x;
  if (e >= E) return;
  atomicAdd(&S[row[e]], t[col[e]]);
}
__global__ void k_out_div(const int* __restrict__ row, const int* __restrict__ col,
                          const float* __restrict__ vori, const float* __restrict__ t,
                          const float* __restrict__ S, float* __restrict__ out, int E) {
  int e = blockIdx.x * blockDim.x + threadIdx.x;
  if (e >= E) return;
  out[e] = vori[e] + t[col[e]] / S[row[e]];
}

extern "C" void kernel_launch(void* const* d_in, const int* in_sizes, int n_in,
                              void* d_out, int out_size, void* d_ws, size_t ws_size,
                              hipStream_t stream) {
  const float* vori = (const float*)d_in[0];
  const float* feat = (const float*)d_in[1];
  const int*   vind = (const int*)d_in[2];
  const float* W    = (const float*)d_in[4];
  const float* mw   = (const float*)d_in[6];

  const int E = in_sizes[0];
  const int H = in_sizes[6] / 2;        // 128
  const int F = in_sizes[4] / H;        // 512
  const int N = in_sizes[1] / F;        // 50000

  const int* row = vind;
  const int* col = vind + E;

  const int nb   = (N + RPB - 1) / RPB; // 391
  const int npad = nb * RPB;

  // ---- workspace:
  //   u2(F) q(N) t(npad) invS(npad) | cnt(nb) pad(8) | rec8(nb*CAP uint2)
  //   | recE(nb*CAP u32)
  float* ws   = (float*)d_ws;
  float* u2   = ws;
  float* q    = u2 + F;
  float* t    = q + N;
  float* invS = t + npad;
  u32*   cnt  = (u32*)(invS + npad);
  size_t hdr  = (size_t)((char*)(cnt + nb + 8) - (char*)d_ws);
  hdr = (hdr + 15) & ~(size_t)15;
  uint2* rec8 = (uint2*)((char*)d_ws + hdr);
  u32*   recE = (u32*)(rec8 + (size_t)nb * CAP);
  size_t need = hdr + (size_t)nb * CAP * (sizeof(uint2) + sizeof(u32));
  size_t need9 = hdr + (size_t)nb * CAP * sizeof(uint2);

  k_prep<<<(F + 255) / 256, 256, 0, stream>>>(W, mw, u2, cnt, F, H, nb + 8);

  if (ws_size >= need && F == 512 && H % 4 == 0 && nb <= NB_MAX) {
    // ---- R12: 4 plain dispatches ----
    k_fused1r<512><<<FG, 1024, 0, stream>>>(row, col, vori, feat, u2, q,
                                            cnt, rec8, recE, E, N, nb);
    k_sum_t<<<nb, 1024, 0, stream>>>(rec8, cnt, q, t);
    k_finish<<<nb, 1024, 0, stream>>>(rec8, recE, cnt, t, (float*)d_out);
  } else if (ws_size >= need9 && F == 512 && H % 4 == 0 && nb <= NB_MAX) {
    // ---- R9 path (verified) ----
    k_fused<<<SB + GB, 1024, 0, stream>>>(row, col, vori, feat, u2, q,
                                          cnt, rec8, E, N, nb, F);
    k_sum_t<<<nb, 1024, 0, stream>>>(rec8, cnt, q, t);
    k_sum_invS<<<nb, 1024, 0, stream>>>(rec8, cnt, t, invS);
    const int e4 = (E + 3) / 4;
    k_out<<<(e4 + 255) / 256, 256, 0, stream>>>(row, col, vori, t, invS,
                                                (float*)d_out, E);
  } else {
    const int eb  = (E + 255) / 256;
    const int nbk = (N + 255) / 256;
    float* S = invS;
    k_gemv_fb<<<(N * 64 + 255) / 256, 256, 0, stream>>>(feat, u2, q, N, F);
    hipMemsetAsync((void*)S, 0, sizeof(float) * (size_t)npad, stream);
    k_scatter_B_at<<<eb, 256, 0, stream>>>(row, col, vori, q, S, E);
    k_node_t<<<nbk, 256, 0, stream>>>(S, t, N);
    hipMemsetAsync((void*)S, 0, sizeof(float) * (size_t)npad, stream);
    k_scatter_S_at<<<eb, 256, 0, stream>>>(row, col, t, S, E);
    k_out_div<<<eb, 256, 0, stream>>>(row, col, vori, t, S, (float*)d_out, E);
  }
}

// Round 4
// 214.722 us; speedup vs baseline: 1.5215x; 1.0083x over previous
//
#include <hip/hip_runtime.h>

// ---------------------------------------------------------------------------
// GenView, round 13.
//
// Algebra (verified R1-R8): per-row softmax cancels emb[row]·w1 and biases.
//   q[n]    = feat[n] . (W @ w2)
//   t[n]    = exp( sum_{e:row=n} v[e]*q[col[e]] )
//   invS[n] = 1 / sum_{e:row=n} t[col[e]]
//   out[e]  = vori[e] + t[col[e]] * invS[row[e]]
//
// History: R9 = 207.8 us (5 dispatches, sort||gemv overlapped in k_fused).
// R11 cooperative mega = 266 us kernel (grid.sync ~60us each -> dead end).
// R12 single-round per-block sort->gemv = 216.5 us; k_fused1r = 62 us with
// VALUBusy 4% / HBM 19%: serializing the phases lost the sort||gemv overlap
// AND 512 blocks false-shared the dense cnt[] reservation lines (16 u32
// counters per 64B line -> device-scope RMW serialization).
// R13 = R9 overlap structure + R12's k_finish fusion + padded counters:
//  - k_fused: SB=256 sort blocks || GB=782 gemv blocks (one dispatch);
//    sort also records edge id (recE). cnt[] strided 16 u32 = 1 line/counter.
//  - k_sum_t: unchanged verified R9 kernel (padded cnt access only).
//  - k_finish: fused invS+out — per bucket gather t[col] into regs
//    (<=3 rec/thread), LDS-sum -> invS, write out[e] from regs. Kills
//    k_out's 9.6 MB re-read + one dispatch gap. 5 dispatches -> 4.
// Bucket sort: row>>7 -> 391 buckets, CAP=3072 (mean fill 2046, 22 sigma).
// ---------------------------------------------------------------------------

typedef unsigned int u32;

#define RPB     128          // rows per bucket
#define CAP     3072         // record slots per bucket (== 3*1024)
#define NB_MAX  512          // max buckets (N <= 65536)
#define CPAD    16           // cnt[] stride in u32 (64B line per counter)
#define SB      256          // sort blocks
#define GB      782          // gemv blocks

// ---- u2[f] = sum_h W[f,h]*mw[H+h]; block 0 also zeros cnt[] ----
__global__ void k_prep(const float* __restrict__ W, const float* __restrict__ mw,
                       float* __restrict__ u2, u32* __restrict__ cnt,
                       int F, int H, int nz) {
  if (blockIdx.x == 0)
    for (int s = threadIdx.x; s < nz; s += blockDim.x) cnt[s] = 0;
  int f = blockIdx.x * blockDim.x + threadIdx.x;
  if (f >= F) return;
  const float4* wr = (const float4*)(W + (size_t)f * H);
  const float4* mv = (const float4*)(mw + H);
  float s = 0.f;
  for (int i = 0; i < H / 4; ++i) {
    float4 a = wr[i], b = mv[i];
    s = fmaf(a.x, b.x, fmaf(a.y, b.y, fmaf(a.z, b.z, fmaf(a.w, b.w, s))));
  }
  u2[f] = s;
}

// ---- fused: blocks [0,SB) bucket-sort edges; blocks [SB,SB+GB) gemv ----
template <int F>
__global__ void __launch_bounds__(1024)
k_fused(const int* __restrict__ row, const int* __restrict__ col,
        const float* __restrict__ v, const float* __restrict__ feat,
        const float* __restrict__ u2, float* __restrict__ q,
        u32* __restrict__ cnt, uint2* __restrict__ rec8,
        u32* __restrict__ recE, int E, int N, int nb) {
  __shared__ u32 h[NB_MAX];
  __shared__ u32 start[NB_MAX];
  const int tid = threadIdx.x;

  if (blockIdx.x < SB) {
    // ---------------- sort path ----------------
    const int chunk = (E + SB - 1) / SB;
    for (int s = tid; s < nb; s += blockDim.x) h[s] = 0;
    __syncthreads();
    const int lo = blockIdx.x * chunk;
    const int hi = min(E, lo + chunk);
    for (int e = lo + tid; e < hi; e += blockDim.x)
      atomicAdd(&h[row[e] >> 7], 1u);
    __syncthreads();
    for (int s = tid; s < nb; s += blockDim.x) {
      u32 c = h[s];
      start[s] = c ? atomicAdd(&cnt[(size_t)s * CPAD], c) : 0u; // 1 line/counter
      h[s] = 0u;                                                // local rank
    }
    __syncthreads();
    for (int e = lo + tid; e < hi; e += blockDim.x) {
      int r = row[e];
      int b = r >> 7;
      u32 rank = atomicAdd(&h[b], 1u);
      u32 off  = min(start[b] + rank, (u32)(CAP - 1));  // memory-safety clamp
      size_t idx = (size_t)b * CAP + off;
      rec8[idx] = make_uint2(((u32)col[e] << 7) | (u32)(r & 127),
                             __float_as_uint(v[e]));
      recE[idx] = (u32)e;
    }
  } else {
    // ---------------- gemv path ----------------
    const int lane = tid & 63;
    const float4 ua = *(const float4*)(u2 + lane * 8);
    const float4 ub = *(const float4*)(u2 + lane * 8 + 4);
    const int wid = (blockIdx.x - SB) * (1024 >> 6) + (tid >> 6);
    const int nw  = GB * (1024 >> 6);
    for (int r = wid; r < N; r += nw) {
      const float* fr = feat + (size_t)r * F + lane * 8;
      float4 a = *(const float4*)fr;
      float4 b = *(const float4*)(fr + 4);
      float s = fmaf(a.x, ua.x, fmaf(a.y, ua.y, fmaf(a.z, ua.z,
                fmaf(a.w, ua.w, fmaf(b.x, ub.x, fmaf(b.y, ub.y,
                fmaf(b.z, ub.z, b.w * ub.w)))))));
      s += __shfl_xor(s, 32);
      s += __shfl_xor(s, 16);
      s += __shfl_xor(s, 8);
      s += __shfl_xor(s, 4);
      s += __shfl_xor(s, 2);
      s += __shfl_xor(s, 1);
      if (lane == 0) q[r] = s;
    }
  }
}

// ---- per-bucket: t[row] = exp( sum v * q[col] )  (verified R9 kernel) ----
__global__ void __launch_bounds__(1024)
k_sum_t(const uint2* __restrict__ rec8, const u32* __restrict__ cnt,
        const float* __restrict__ q, float* __restrict__ t) {
  __shared__ float acc[RPB];
  const int b = blockIdx.x;
  const int tid = threadIdx.x;
  if (tid < RPB) acc[tid] = 0.f;
  __syncthreads();
  const u32 lo = (u32)b * CAP;
  const u32 n  = min(cnt[(size_t)b * CPAD], (u32)CAP);
  for (u32 i = tid; i < n; i += blockDim.x) {
    uint2 rr = rec8[lo + i];
    atomicAdd(&acc[rr.x & 127], q[rr.x >> 7] * __uint_as_float(rr.y));
  }
  __syncthreads();
  if (tid < RPB) t[b * RPB + tid] = __expf(acc[tid]);
}

// ---- per-bucket fused: invS in LDS, then out[e] = v + t[col]*invS[row] ----
// CAP == 3*1024 so <=3 records/thread, all held in registers (static idx).
__global__ void __launch_bounds__(1024)
k_finish(const uint2* __restrict__ rec8, const u32* __restrict__ recE,
         const u32* __restrict__ cnt, const float* __restrict__ t,
         float* __restrict__ out) {
  __shared__ float acc[RPB];
  const int b = blockIdx.x;
  const int tid = threadIdx.x;
  if (tid < RPB) acc[tid] = 0.f;
  __syncthreads();
  const u32 lo = (u32)b * CAP;
  const u32 n  = min(cnt[(size_t)b * CPAD], (u32)CAP);
  bool  ok[3];
  u32   cr[3], ee[3];
  float vv[3], tc[3];
#pragma unroll
  for (int k = 0; k < 3; ++k) {
    u32 i = (u32)tid + (u32)k * 1024u;
    ok[k] = (i < n);
    cr[k] = 0; ee[k] = 0; vv[k] = 0.f; tc[k] = 0.f;
    if (ok[k]) {
      uint2 rr = rec8[lo + i];
      cr[k] = rr.x;
      vv[k] = __uint_as_float(rr.y);
      ee[k] = recE[lo + i];
      float tv = t[rr.x >> 7];
      tc[k] = tv;
      atomicAdd(&acc[rr.x & 127], tv);
    }
  }
  __syncthreads();
  if (tid < RPB) acc[tid] = 1.0f / acc[tid];   // empty rows never read
  __syncthreads();
#pragma unroll
  for (int k = 0; k < 3; ++k)
    if (ok[k])
      out[ee[k]] = vv[k] + tc[k] * acc[cr[k] & 127];
}

// ===================== fallback: R9 backend (padded cnt) =====================

__global__ void __launch_bounds__(1024)
k_sum_invS(const uint2* __restrict__ rec8, const u32* __restrict__ cnt,
           const float* __restrict__ t, float* __restrict__ invS) {
  __shared__ float acc[RPB];
  const int b = blockIdx.x;
  const int tid = threadIdx.x;
  if (tid < RPB) acc[tid] = 0.f;
  __syncthreads();
  const u32 lo = (u32)b * CAP;
  const u32 n  = min(cnt[(size_t)b * CPAD], (u32)CAP);
  for (u32 i = tid; i < n; i += blockDim.x) {
    uint2 rr = rec8[lo + i];
    atomicAdd(&acc[rr.x & 127], t[rr.x >> 7]);
  }
  __syncthreads();
  if (tid < RPB) invS[b * RPB + tid] = 1.0f / acc[tid];
}

__global__ void k_out(const int* __restrict__ row, const int* __restrict__ col,
                      const float* __restrict__ vori, const float* __restrict__ t,
                      const float* __restrict__ invS, float* __restrict__ out,
                      int E) {
  int e4 = blockIdx.x * blockDim.x + threadIdx.x;
  int e  = e4 * 4;
  if (e + 3 < E) {
    int4   r4 = *(const int4*)(row + e);
    int4   c4 = *(const int4*)(col + e);
    float4 v4 = *(const float4*)(vori + e);
    float4 o;
    o.x = v4.x + t[c4.x] * invS[r4.x];
    o.y = v4.y + t[c4.y] * invS[r4.y];
    o.z = v4.z + t[c4.z] * invS[r4.z];
    o.w = v4.w + t[c4.w] * invS[r4.w];
    *(float4*)(out + e) = o;
  } else {
    for (; e < E; ++e)
      out[e] = vori[e] + t[col[e]] * invS[row[e]];
  }
}

// ---- last-resort fallback (ws too small / shape mismatch): global-atomic ----
__global__ void k_gemv_fb(const float* __restrict__ feat, const float* __restrict__ u2,
                          float* __restrict__ q, int N, int F) {
  const int lane = threadIdx.x & 63;
  const int wave = (blockIdx.x * blockDim.x + threadIdx.x) >> 6;
  if (wave >= N) return;
  const float* fr = feat + (size_t)wave * F;
  float a = 0.f;
  for (int i = lane; i < F; i += 64) a = fmaf(fr[i], u2[i], a);
  for (int off = 32; off; off >>= 1) a += __shfl_xor(a, off);
  if (lane == 0) q[wave] = a;
}
__global__ void k_scatter_B_at(const int* __restrict__ row, const int* __restrict__ col,
                               const float* __restrict__ v, const float* __restrict__ q,
                               float* __restrict__ B, int E) {
  int e = blockIdx.x * blockDim.x + threadIdx.x;
  if (e >= E) return;
  atomicAdd(&B[row[e]], v[e] * q[col[e]]);
}
__global__ void k_node_t(const float* __restrict__ B, float* __restrict__ t, int N) {
  int n = blockIdx.x * blockDim.x + threadIdx.x;
  if (n < N) t[n] = __expf(B[n]);
}
__global__ void k_scatter_S_at(const int* __restrict__ row, const int* __restrict__ col,
                               const float* __restrict__ t, float* __restrict__ S, int E) {
  int e = blockIdx.x * blockDim.x + threadIdx.x;
  if (e >= E) return;
  atomicAdd(&S[row[e]], t[col[e]]);
}
__global__ void k_out_div(const int* __restrict__ row, const int* __restrict__ col,
                          const float* __restrict__ vori, const float* __restrict__ t,
                          const float* __restrict__ S, float* __restrict__ out, int E) {
  int e = blockIdx.x * blockDim.x + threadIdx.x;
  if (e >= E) return;
  out[e] = vori[e] + t[col[e]] / S[row[e]];
}

extern "C" void kernel_launch(void* const* d_in, const int* in_sizes, int n_in,
                              void* d_out, int out_size, void* d_ws, size_t ws_size,
                              hipStream_t stream) {
  const float* vori = (const float*)d_in[0];
  const float* feat = (const float*)d_in[1];
  const int*   vind = (const int*)d_in[2];
  const float* W    = (const float*)d_in[4];
  const float* mw   = (const float*)d_in[6];

  const int E = in_sizes[0];
  const int H = in_sizes[6] / 2;        // 128
  const int F = in_sizes[4] / H;        // 512
  const int N = in_sizes[1] / F;        // 50000

  const int* row = vind;
  const int* col = vind + E;

  const int nb   = (N + RPB - 1) / RPB; // 391
  const int npad = nb * RPB;

  // ---- workspace:
  //   u2(F) q(N) t(npad) invS(npad) | cnt(nb*CPAD u32) pad | rec8(nb*CAP uint2)
  //   | recE(nb*CAP u32)
  float* ws   = (float*)d_ws;
  float* u2   = ws;
  float* q    = u2 + F;
  float* t    = q + N;
  float* invS = t + npad;
  u32*   cnt  = (u32*)(invS + npad);
  size_t hdr  = (size_t)((char*)(cnt + (size_t)nb * CPAD + 16) - (char*)d_ws);
  hdr = (hdr + 63) & ~(size_t)63;
  uint2* rec8 = (uint2*)((char*)d_ws + hdr);
  u32*   recE = (u32*)(rec8 + (size_t)nb * CAP);
  size_t need  = hdr + (size_t)nb * CAP * (sizeof(uint2) + sizeof(u32));
  size_t need9 = hdr + (size_t)nb * CAP * sizeof(uint2);

  k_prep<<<(F + 255) / 256, 256, 0, stream>>>(W, mw, u2, cnt, F, H, nb * CPAD);

  if (ws_size >= need && F == 512 && H % 4 == 0 && nb <= NB_MAX) {
    // ---- R13: 4 dispatches, sort||gemv overlapped, fused finish ----
    k_fused<512><<<SB + GB, 1024, 0, stream>>>(row, col, vori, feat, u2, q,
                                               cnt, rec8, recE, E, N, nb);
    k_sum_t<<<nb, 1024, 0, stream>>>(rec8, cnt, q, t);
    k_finish<<<nb, 1024, 0, stream>>>(rec8, recE, cnt, t, (float*)d_out);
  } else if (ws_size >= need9 && F == 512 && H % 4 == 0 && nb <= NB_MAX) {
    // ---- R9-like path (no recE room): separate invS + out ----
    k_fused<512><<<SB + GB, 1024, 0, stream>>>(row, col, vori, feat, u2, q,
                                               cnt, rec8, recE, E, N, nb);
    k_sum_t<<<nb, 1024, 0, stream>>>(rec8, cnt, q, t);
    k_sum_invS<<<nb, 1024, 0, stream>>>(rec8, cnt, t, invS);
    const int e4 = (E + 3) / 4;
    k_out<<<(e4 + 255) / 256, 256, 0, stream>>>(row, col, vori, t, invS,
                                                (float*)d_out, E);
  } else {
    const int eb  = (E + 255) / 256;
    const int nbk = (N + 255) / 256;
    float* S = invS;
    k_gemv_fb<<<(N * 64 + 255) / 256, 256, 0, stream>>>(feat, u2, q, N, F);
    hipMemsetAsync((void*)S, 0, sizeof(float) * (size_t)npad, stream);
    k_scatter_B_at<<<eb, 256, 0, stream>>>(row, col, vori, q, S, E);
    k_node_t<<<nbk, 256, 0, stream>>>(S, t, N);
    hipMemsetAsync((void*)S, 0, sizeof(float) * (size_t)npad, stream);
    k_scatter_S_at<<<eb, 256, 0, stream>>>(row, col, t, S, E);
    k_out_div<<<eb, 256, 0, stream>>>(row, col, vori, t, S, (float*)d_out, E);
  }
}